// Round 6
// baseline (2356.248 us; speedup 1.0000x reference)
//
#include <hip/hip_runtime.h>
#include <math.h>

#define NN 6144
#define DSZ 2048
#define TSZ 4096
#define NE 1048576
#define NE_TOT (NE + NN)
#define NEG_SLOPE 0.2f
#define GGAMMA 0.03125f
#define LDCAT 896  // concatenated K for fused gram: 256*3 + 128

typedef float floatx4 __attribute__((ext_vector_type(4)));
typedef __bf16 bf16x8 __attribute__((ext_vector_type(8)));

// ---------------- CSR build (counting sort by dst) ----------------
__global__ void hist_kernel(const int* __restrict__ ei, int* __restrict__ cnt) {
    int e = blockIdx.x * blockDim.x + threadIdx.x;
    if (e >= NE_TOT) return;
    int d = (e < NE) ? ei[NE + e] : (e - NE);
    atomicAdd(&cnt[d], 1);
}

__global__ void scan_kernel(const int* __restrict__ cnt, int* __restrict__ row_ofs) {
    __shared__ int part[1024];
    int t = threadIdx.x;
    int local[6];
    int s = 0;
#pragma unroll
    for (int i = 0; i < 6; i++) { local[i] = s; s += cnt[t * 6 + i]; }
    part[t] = s;
    __syncthreads();
    for (int off = 1; off < 1024; off <<= 1) {
        int v = (t >= off) ? part[t - off] : 0;
        __syncthreads();
        part[t] += v;
        __syncthreads();
    }
    int base = (t == 0) ? 0 : part[t - 1];
#pragma unroll
    for (int i = 0; i < 6; i++) row_ofs[t * 6 + i] = base + local[i];
    if (t == 1023) row_ofs[NN] = part[1023];
}

__global__ void copy_cursor(const int* __restrict__ row_ofs, int* __restrict__ cursor) {
    int i = blockIdx.x * blockDim.x + threadIdx.x;
    if (i < NN) cursor[i] = row_ofs[i];
}

__global__ void scatter_kernel(const int* __restrict__ ei, int* __restrict__ cursor,
                               int* __restrict__ col) {
    int e = blockIdx.x * blockDim.x + threadIdx.x;
    if (e >= NE_TOT) return;
    int s, d;
    if (e < NE) { s = ei[e]; d = ei[NE + e]; } else { s = e - NE; d = s; }
    int pos = atomicAdd(&cursor[d], 1);
    col[pos] = s;
}

// ---------------- generic fp32 GEMM (fallback only) ----------------
template <bool ATOMIC>
__global__ __launch_bounds__(256) void gemm64(const float* __restrict__ A,
                                              const float* __restrict__ B,
                                              float* __restrict__ C,
                                              int M, int N, int K) {
    __shared__ float As[16][68];
    __shared__ float Bs[16][68];
    const int tid = threadIdx.x;
    const int tn = tid & 15, tm = tid >> 4;
    const int bm = blockIdx.y * 64, bn = blockIdx.x * 64;
    const int ar = tid >> 2, ac = (tid & 3) * 4;
    const int br = tid >> 4, bc = (tid & 15) * 4;
    int kbeg = 0, kend = K;
    if constexpr (ATOMIC) {
        int klen = K / gridDim.z;
        kbeg = blockIdx.z * klen;
        kend = kbeg + klen;
    }
    const float* Ap = A + (size_t)(bm + ar) * K + ac;
    const float* Bp = B + (size_t)br * N + bn + bc;
    float acc[4][4] = {};
    for (int k0 = kbeg; k0 < kend; k0 += 16) {
        float4 av = *(const float4*)(Ap + k0);
        float4 bv = *(const float4*)(Bp + (size_t)k0 * N);
        As[ac + 0][ar] = av.x; As[ac + 1][ar] = av.y;
        As[ac + 2][ar] = av.z; As[ac + 3][ar] = av.w;
        *(float4*)&Bs[br][bc] = bv;
        __syncthreads();
#pragma unroll
        for (int k = 0; k < 16; k++) {
            float4 a4 = *(const float4*)&As[k][tm * 4];
            float4 b4 = *(const float4*)&Bs[k][tn * 4];
            float aa[4] = {a4.x, a4.y, a4.z, a4.w};
            float bb[4] = {b4.x, b4.y, b4.z, b4.w};
#pragma unroll
            for (int i = 0; i < 4; i++)
#pragma unroll
                for (int j = 0; j < 4; j++) acc[i][j] = fmaf(aa[i], bb[j], acc[i][j]);
        }
        __syncthreads();
    }
#pragma unroll
    for (int i = 0; i < 4; i++) {
        float* cp = C + (size_t)(bm + tm * 4 + i) * N + bn + tn * 4;
        if constexpr (ATOMIC) {
#pragma unroll
            for (int j = 0; j < 4; j++) atomicAdd(cp + j, acc[i][j]);
        } else {
            *(float4*)cp = make_float4(acc[i][0], acc[i][1], acc[i][2], acc[i][3]);
        }
    }
}

// ---------------- bf16 hi/lo split helpers ----------------
__device__ __forceinline__ ushort bf16_rne(float x) {
    unsigned u = __float_as_uint(x);
    unsigned r = (u + 0x7fffu + ((u >> 16) & 1u)) >> 16;
    return (ushort)r;
}

__global__ void split_rm(const float* __restrict__ in, ushort* __restrict__ hi,
                         ushort* __restrict__ lo, size_t n4) {
    for (size_t i = (size_t)blockIdx.x * blockDim.x + threadIdx.x; i < n4;
         i += (size_t)gridDim.x * blockDim.x) {
        float4 v = ((const float4*)in)[i];
        float vv[4] = {v.x, v.y, v.z, v.w};
        ushort h[4], l[4];
#pragma unroll
        for (int j = 0; j < 4; j++) {
            h[j] = bf16_rne(vv[j]);
            float hf = __uint_as_float((unsigned)h[j] << 16);
            l[j] = bf16_rne(vv[j] - hf);
        }
        ((ushort4*)hi)[i] = make_ushort4(h[0], h[1], h[2], h[3]);
        ((ushort4*)lo)[i] = make_ushort4(l[0], l[1], l[2], l[3]);
    }
}

// transpose + split: fp32 [R][C] -> hiT/loT bf16 [C][R]
__global__ void split_T(const float* __restrict__ in, ushort* __restrict__ hiT,
                        ushort* __restrict__ loT, int R, int C) {
    __shared__ float tile[32][33];
    int bx = blockIdx.x * 32, by = blockIdx.y * 32;
    int tx = threadIdx.x & 31, ty = threadIdx.x >> 5;  // 32x8
#pragma unroll
    for (int k = 0; k < 32; k += 8)
        tile[ty + k][tx] = in[(size_t)(by + ty + k) * C + bx + tx];
    __syncthreads();
#pragma unroll
    for (int k = 0; k < 32; k += 8) {
        float v = tile[tx][ty + k];
        ushort h = bf16_rne(v);
        float hf = __uint_as_float((unsigned)h << 16);
        ushort l = bf16_rne(v - hf);
        size_t o = (size_t)(bx + ty + k) * R + by + tx;
        hiT[o] = h;
        loT[o] = l;
    }
}

// ---------------- bf16x3 MFMA GEMM: C[M][N] = A[M][K] @ B[N][K]^T ----------------
// EPI=0: C = result. EPI=2: atomicAdd (split-K over gridDim.z).
__device__ __forceinline__ void gl_lds16(const void* g, void* l) {
    __builtin_amdgcn_global_load_lds(
        (const __attribute__((address_space(1))) unsigned int*)g,
        (__attribute__((address_space(3))) unsigned int*)l, 16, 0, 0);
}

template <int EPI>
__global__ __launch_bounds__(256) void gemm_bt_x3(
    const ushort* __restrict__ Ah, const ushort* __restrict__ Al,
    const ushort* __restrict__ Bh, const ushort* __restrict__ Bl,
    float* __restrict__ C, int M, int N, int K) {
    __shared__ ushort lds[4][4096];  // Ah,Al,Bh,Bl tiles: 128 rows x 32 bf16 (64 B/row)
    const int t = threadIdx.x;
    const int bm = blockIdx.y * 128, bn = blockIdx.x * 128;

    const int srow = t >> 2;
    const int scb = (t & 3) << 4;
    const int gcb = scb ^ (((srow >> 1) & 3) << 4);  // inverse swizzle on global source
    const int wid = t >> 6, lane = t & 63;

    int kbeg = 0, kend = K;
    if (gridDim.z > 1) {
        int klen = K / gridDim.z;
        kbeg = blockIdx.z * klen;
        kend = kbeg + klen;
    }

    const ushort* srcs[4] = {Ah, Al, Bh, Bl};
    const char* g[8];
    ushort* lp[8];
#pragma unroll
    for (int b = 0; b < 4; b++) {
        int rb = (b < 2) ? bm : bn;
#pragma unroll
        for (int i = 0; i < 2; i++) {
            g[b * 2 + i] = (const char*)srcs[b] + ((size_t)(rb + i * 64 + srow) * K) * 2 + gcb;
            lp[b * 2 + i] = &lds[b][i * 2048 + wid * 512];  // wave-uniform; HW adds lane*16B
        }
    }

    floatx4 acc[4][4];
#pragma unroll
    for (int m = 0; m < 4; m++)
#pragma unroll
        for (int n = 0; n < 4; n++) acc[m][n] = (floatx4){0.f, 0.f, 0.f, 0.f};

    const int wr = (wid >> 1) << 6, wc = (wid & 1) << 6;
    const int fr = lane & 15, kh = lane >> 4;
    const int cbf = (((kh << 4) ^ (((fr >> 1) & 3) << 4)) >> 1);

    for (int k0 = kbeg; k0 < kend; k0 += 32) {
#pragma unroll
        for (int q = 0; q < 8; q++) gl_lds16(g[q] + (size_t)k0 * 2, lp[q]);
        __syncthreads();
        bf16x8 bhf[4], blf[4];
#pragma unroll
        for (int n = 0; n < 4; n++) {
            int r = wc + n * 16 + fr;
            bhf[n] = *(const bf16x8*)&lds[2][r * 32 + cbf];
            blf[n] = *(const bf16x8*)&lds[3][r * 32 + cbf];
        }
#pragma unroll
        for (int m = 0; m < 4; m++) {
            int r = wr + m * 16 + fr;
            bf16x8 ahf = *(const bf16x8*)&lds[0][r * 32 + cbf];
            bf16x8 alf = *(const bf16x8*)&lds[1][r * 32 + cbf];
#pragma unroll
            for (int n = 0; n < 4; n++) {
                acc[m][n] = __builtin_amdgcn_mfma_f32_16x16x32_bf16(ahf, bhf[n], acc[m][n], 0, 0, 0);
                acc[m][n] = __builtin_amdgcn_mfma_f32_16x16x32_bf16(ahf, blf[n], acc[m][n], 0, 0, 0);
                acc[m][n] = __builtin_amdgcn_mfma_f32_16x16x32_bf16(alf, bhf[n], acc[m][n], 0, 0, 0);
            }
        }
        __syncthreads();
    }

#pragma unroll
    for (int m = 0; m < 4; m++) {
#pragma unroll
        for (int n = 0; n < 4; n++) {
#pragma unroll
            for (int r = 0; r < 4; r++) {
                int gr = bm + wr + m * 16 + kh * 4 + r;  // C/D: row=(lane>>4)*4+reg
                int gc = bn + wc + n * 16 + fr;          //      col=lane&15
                size_t idx = (size_t)gr * N + gc;
                if constexpr (EPI == 0) C[idx] = acc[m][n][r];
                else atomicAdd(&C[idx], acc[m][n][r]);
            }
        }
    }
}

// ---------------- fused 4-layer GIP gram: Kout = 0.2*sim + sum_l p_l*gip_l ----------------
// Yh/Yl: [M][LDCAT] bf16 hi/lo, layer l at cols [l*256, l*256+len_l).
__global__ __launch_bounds__(256) void gram_fused(
    const ushort* __restrict__ Yh, const ushort* __restrict__ Yl,
    const float* __restrict__ sim, float* __restrict__ Kout,
    const float* __restrict__ rbufs,  // [4][M]
    const float* __restrict__ md0s,   // [4]
    int M) {
    __shared__ ushort lds[4][4096];
    const int t = threadIdx.x;
    const int bm = blockIdx.y * 128, bn = blockIdx.x * 128;
    const int srow = t >> 2;
    const int scb = (t & 3) << 4;
    const int gcb = scb ^ (((srow >> 1) & 3) << 4);
    const int wid = t >> 6, lane = t & 63;

    const ushort* srcs[4] = {Yh, Yl, Yh, Yl};
    const char* g[8];
    ushort* lp[8];
#pragma unroll
    for (int b = 0; b < 4; b++) {
        int rb = (b < 2) ? bm : bn;
#pragma unroll
        for (int i = 0; i < 2; i++) {
            g[b * 2 + i] = (const char*)srcs[b] + ((size_t)(rb + i * 64 + srow) * LDCAT) * 2 + gcb;
            lp[b * 2 + i] = &lds[b][i * 2048 + wid * 512];
        }
    }

    const int wr = (wid >> 1) << 6, wc = (wid & 1) << 6;
    const int fr = lane & 15, kh = lane >> 4;
    const int cbf = (((kh << 4) ^ (((fr >> 1) & 3) << 4)) >> 1);

    floatx4 epi[4][4];
#pragma unroll
    for (int m = 0; m < 4; m++)
#pragma unroll
        for (int n = 0; n < 4; n++) epi[m][n] = (floatx4){0.f, 0.f, 0.f, 0.f};

#pragma unroll
    for (int l = 0; l < 4; l++) {
        const int kofs = l * 256;
        const int klen = (l == 3) ? 128 : 256;
        const float pl = (l == 0) ? 1.0f : (l == 1) ? 0.5f : (l == 2) ? 0.333f : 0.25f;
        floatx4 acc[4][4];
#pragma unroll
        for (int m = 0; m < 4; m++)
#pragma unroll
            for (int n = 0; n < 4; n++) acc[m][n] = (floatx4){0.f, 0.f, 0.f, 0.f};
#pragma unroll 1
        for (int k0 = kofs; k0 < kofs + klen; k0 += 32) {
#pragma unroll
            for (int q = 0; q < 8; q++) gl_lds16(g[q] + (size_t)k0 * 2, lp[q]);
            __syncthreads();
            bf16x8 bhf[4], blf[4];
#pragma unroll
            for (int n = 0; n < 4; n++) {
                int r = wc + n * 16 + fr;
                bhf[n] = *(const bf16x8*)&lds[2][r * 32 + cbf];
                blf[n] = *(const bf16x8*)&lds[3][r * 32 + cbf];
            }
#pragma unroll
            for (int m = 0; m < 4; m++) {
                int r = wr + m * 16 + fr;
                bf16x8 ahf = *(const bf16x8*)&lds[0][r * 32 + cbf];
                bf16x8 alf = *(const bf16x8*)&lds[1][r * 32 + cbf];
#pragma unroll
                for (int n = 0; n < 4; n++) {
                    acc[m][n] = __builtin_amdgcn_mfma_f32_16x16x32_bf16(ahf, bhf[n], acc[m][n], 0, 0, 0);
                    acc[m][n] = __builtin_amdgcn_mfma_f32_16x16x32_bf16(ahf, blf[n], acc[m][n], 0, 0, 0);
                    acc[m][n] = __builtin_amdgcn_mfma_f32_16x16x32_bf16(alf, bhf[n], acc[m][n], 0, 0, 0);
                }
            }
            __syncthreads();
        }
        float sc = GGAMMA / md0s[l];
        const float* rb_ = rbufs + (size_t)l * M;
#pragma unroll
        for (int m = 0; m < 4; m++) {
#pragma unroll
            for (int r = 0; r < 4; r++) {
                float ri = rb_[bm + wr + m * 16 + kh * 4 + r];
#pragma unroll
                for (int n = 0; n < 4; n++) {
                    float rj = rb_[bn + wc + n * 16 + fr];
                    epi[m][n][r] += pl * expf(-(ri + rj - 2.f * acc[m][n][r]) * sc);
                }
            }
        }
    }

#pragma unroll
    for (int m = 0; m < 4; m++) {
#pragma unroll
        for (int n = 0; n < 4; n++) {
#pragma unroll
            for (int r = 0; r < 4; r++) {
                int gr = bm + wr + m * 16 + kh * 4 + r;
                int gc = bn + wc + n * 16 + fr;
                size_t idx = (size_t)gr * M + gc;
                Kout[idx] = 0.2f * sim[idx] + epi[m][n][r];
            }
        }
    }
}

// ---------------- per-node attention scalars ----------------
__global__ void attn_scores(const float* __restrict__ z, const float* __restrict__ a_src,
                            const float* __restrict__ a_dst, float* __restrict__ s_src,
                            float* __restrict__ s_dst, int Fout, int F) {
    int n = blockIdx.x, t = threadIdx.x;
    __shared__ float r1[256], r2[256];
    float v = (t < Fout) ? z[(size_t)n * Fout + t] : 0.f;
    r1[t] = (t < Fout) ? v * a_src[t] : 0.f;
    r2[t] = (t < Fout) ? v * a_dst[t] : 0.f;
    __syncthreads();
    for (int off = F >> 1; off > 0; off >>= 1) {
        if ((t & (F - 1)) < off) { r1[t] += r1[t + off]; r2[t] += r2[t + off]; }
        __syncthreads();
    }
    if (t < Fout && (t & (F - 1)) == 0) {
        int h = t / F;
        s_src[n * 4 + h] = r1[t];
        s_dst[n * 4 + h] = r2[t];
    }
}

// ---------------- GAT aggregate ----------------
template <int FOUT, int F>
__global__ __launch_bounds__(256) void gat_aggregate(
    const float* __restrict__ z, const int* __restrict__ row_ofs,
    const int* __restrict__ col, const float* __restrict__ s_src,
    const float* __restrict__ s_dst, const float* __restrict__ bias,
    float* __restrict__ H) {
    constexpr int VPL = FOUT / 64;
    int wave = threadIdx.x >> 6, lane = threadIdx.x & 63;
    int n = blockIdx.x * 4 + wave;
    int beg = row_ofs[n], end = row_ofs[n + 1];
    int f0 = lane * VPL;
    int h = f0 / F;
    float4 sd4 = *(const float4*)&s_dst[n * 4];
    float mx[4] = {-__builtin_inff(), -__builtin_inff(), -__builtin_inff(), -__builtin_inff()};
    for (int e = beg + lane; e < end; e += 64) {
        int s = col[e];
        float4 ss = *(const float4*)&s_src[s * 4];
        float l0 = ss.x + sd4.x; l0 = l0 > 0.f ? l0 : NEG_SLOPE * l0;
        float l1 = ss.y + sd4.y; l1 = l1 > 0.f ? l1 : NEG_SLOPE * l1;
        float l2 = ss.z + sd4.z; l2 = l2 > 0.f ? l2 : NEG_SLOPE * l2;
        float l3 = ss.w + sd4.w; l3 = l3 > 0.f ? l3 : NEG_SLOPE * l3;
        mx[0] = fmaxf(mx[0], l0); mx[1] = fmaxf(mx[1], l1);
        mx[2] = fmaxf(mx[2], l2); mx[3] = fmaxf(mx[3], l3);
    }
#pragma unroll
    for (int off = 32; off > 0; off >>= 1) {
#pragma unroll
        for (int hh = 0; hh < 4; hh++) mx[hh] = fmaxf(mx[hh], __shfl_xor(mx[hh], off));
    }
    float mh = (h == 0) ? mx[0] : (h == 1) ? mx[1] : (h == 2) ? mx[2] : mx[3];
    float sdh = (h == 0) ? sd4.x : (h == 1) ? sd4.y : (h == 2) ? sd4.z : sd4.w;
    float acc[VPL] = {};
    float wsum = 0.f;
    for (int e = beg; e < end; e++) {
        int s = col[e];
        float l = s_src[s * 4 + h] + sdh;
        l = l > 0.f ? l : NEG_SLOPE * l;
        float w = expf(l - mh);
        wsum += w;
        const float* zp = z + (size_t)s * FOUT + f0;
        if constexpr (VPL == 4) {
            float4 zv = *(const float4*)zp;
            acc[0] = fmaf(w, zv.x, acc[0]); acc[1] = fmaf(w, zv.y, acc[1]);
            acc[2] = fmaf(w, zv.z, acc[2]); acc[3] = fmaf(w, zv.w, acc[3]);
        } else {
            float2 zv = *(const float2*)zp;
            acc[0] = fmaf(w, zv.x, acc[0]); acc[1] = fmaf(w, zv.y, acc[1]);
        }
    }
    float inv = 1.f / wsum;
#pragma unroll
    for (int i = 0; i < VPL; i++) {
        float o = acc[i] * inv + bias[f0 + i];
        H[(size_t)n * FOUT + f0 + i] = o > 0.f ? o : 0.f;
    }
}

// ---------------- GIP row normalize -> hi/lo bf16 concat + row sq-norm + md0 atomic ----
__global__ void gip_norm_split(const float* __restrict__ Y, ushort* __restrict__ Yh,
                               ushort* __restrict__ Yl, float* __restrict__ r,
                               float* __restrict__ md0p, float invM,
                               int Fout, int kofs) {
    int row = blockIdx.x, t = threadIdx.x;  // blockDim.x == Fout
    __shared__ float s1[256], s2[256];
    float v = Y[(size_t)row * Fout + t];
    s1[t] = v; s2[t] = v;
    __syncthreads();
    for (int off = blockDim.x >> 1; off > 0; off >>= 1) {
        if (t < off) {
            s1[t] = fminf(s1[t], s1[t + off]);
            s2[t] = fmaxf(s2[t], s2[t + off]);
        }
        __syncthreads();
    }
    float mn = s1[0], mx = s2[0];
    float rng = mx - mn;
    if (rng == 0.f) rng = 1.f;
    float yn = (v - mn) / rng;
    ushort h = bf16_rne(yn);
    float hf = __uint_as_float((unsigned)h << 16);
    ushort lo = bf16_rne(yn - hf);
    size_t o = (size_t)row * LDCAT + kofs + t;
    Yh[o] = h;
    Yl[o] = lo;
    __syncthreads();
    s1[t] = yn * yn;
    __syncthreads();
    for (int off = blockDim.x >> 1; off > 0; off >>= 1) {
        if (t < off) s1[t] += s1[t + off];
        __syncthreads();
    }
    if (t == 0) {
        r[row] = s1[0];
        atomicAdd(md0p, s1[0] * invM);
    }
}

// fp32 variant (fallback path)
__global__ void gip_norm(const float* __restrict__ Y, float* __restrict__ Yn,
                         float* __restrict__ r, int Fout) {
    int row = blockIdx.x, t = threadIdx.x;
    __shared__ float s1[256], s2[256];
    float v = Y[(size_t)row * Fout + t];
    s1[t] = v; s2[t] = v;
    __syncthreads();
    for (int off = blockDim.x >> 1; off > 0; off >>= 1) {
        if (t < off) {
            s1[t] = fminf(s1[t], s1[t + off]);
            s2[t] = fmaxf(s2[t], s2[t + off]);
        }
        __syncthreads();
    }
    float mn = s1[0], mx = s2[0];
    float rng = mx - mn;
    if (rng == 0.f) rng = 1.f;
    float yn = (v - mn) / rng;
    Yn[(size_t)row * Fout + t] = yn;
    __syncthreads();
    s1[t] = yn * yn;
    __syncthreads();
    for (int off = blockDim.x >> 1; off > 0; off >>= 1) {
        if (t < off) s1[t] += s1[t + off];
        __syncthreads();
    }
    if (t == 0) r[row] = s1[0];
}

__global__ void mean_reduce(const float* __restrict__ r, float* __restrict__ md0, int M) {
    __shared__ float s[1024];
    int t = threadIdx.x;
    float acc = 0.f;
    for (int i = t; i < M; i += 1024) acc += r[i];
    s[t] = acc;
    __syncthreads();
    for (int off = 512; off > 0; off >>= 1) {
        if (t < off) s[t] += s[t + off];
        __syncthreads();
    }
    if (t == 0) md0[0] = s[0] / (float)M;
}

// ---------------- fp32 gram (fallback only) ----------------
__global__ __launch_bounds__(256) void gram64(const float* __restrict__ Y,
                                              float* __restrict__ Kacc,
                                              const float* __restrict__ rbuf,
                                              const float* __restrict__ md0buf,
                                              float p, int M, int K) {
    __shared__ float As[16][68];
    __shared__ float Bs[16][68];
    const int tid = threadIdx.x;
    const int tn = tid & 15, tm = tid >> 4;
    const int bm = blockIdx.y * 64, bn = blockIdx.x * 64;
    const int ar = tid >> 2, ac = (tid & 3) * 4;
    const float* Ap = Y + (size_t)(bm + ar) * K + ac;
    const float* Bp = Y + (size_t)(bn + ar) * K + ac;
    float acc[4][4] = {};
    for (int k0 = 0; k0 < K; k0 += 16) {
        float4 av = *(const float4*)(Ap + k0);
        float4 bv = *(const float4*)(Bp + k0);
        As[ac + 0][ar] = av.x; As[ac + 1][ar] = av.y;
        As[ac + 2][ar] = av.z; As[ac + 3][ar] = av.w;
        Bs[ac + 0][ar] = bv.x; Bs[ac + 1][ar] = bv.y;
        Bs[ac + 2][ar] = bv.z; Bs[ac + 3][ar] = bv.w;
        __syncthreads();
#pragma unroll
        for (int k = 0; k < 16; k++) {
            float4 a4 = *(const float4*)&As[k][tm * 4];
            float4 b4 = *(const float4*)&Bs[k][tn * 4];
            float aa[4] = {a4.x, a4.y, a4.z, a4.w};
            float bb[4] = {b4.x, b4.y, b4.z, b4.w};
#pragma unroll
            for (int i = 0; i < 4; i++)
#pragma unroll
                for (int j = 0; j < 4; j++) acc[i][j] = fmaf(aa[i], bb[j], acc[i][j]);
        }
        __syncthreads();
    }
    float sc = GGAMMA / md0buf[0];
    float ri[4], rj[4];
#pragma unroll
    for (int i = 0; i < 4; i++) ri[i] = rbuf[bm + tm * 4 + i];
#pragma unroll
    for (int j = 0; j < 4; j++) rj[j] = rbuf[bn + tn * 4 + j];
#pragma unroll
    for (int i = 0; i < 4; i++) {
#pragma unroll
        for (int j = 0; j < 4; j++) {
            float val = p * expf(-(ri[i] + rj[j] - 2.f * acc[i][j]) * sc);
            size_t idx = (size_t)(bm + tm * 4 + i) * M + bn + tn * 4 + j;
            Kacc[idx] += val;
        }
    }
}

// ---------------- misc elementwise ----------------
__global__ void scale_copy(const float* __restrict__ src, float* __restrict__ dst,
                           float p, size_t n) {
    for (size_t i = (size_t)blockIdx.x * blockDim.x + threadIdx.x; i < n;
         i += (size_t)gridDim.x * blockDim.x)
        dst[i] = p * src[i];
}

__global__ void init_min(unsigned* minb) {
    if (threadIdx.x == 0 && blockIdx.x == 0) { minb[0] = 0x7f800000u; minb[1] = 0x7f800000u; }
}

__global__ void min_nonzero(const float* __restrict__ Km, unsigned* __restrict__ minb,
                            size_t total) {
    unsigned lm = 0x7f800000u;
    for (size_t i = (size_t)blockIdx.x * blockDim.x + threadIdx.x; i < total;
         i += (size_t)gridDim.x * blockDim.x) {
        float v = fabsf(Km[i]);
        if (v != 0.f) lm = min(lm, __float_as_uint(v));
    }
#pragma unroll
    for (int off = 32; off > 0; off >>= 1)
        lm = min(lm, (unsigned)__shfl_xor((int)lm, off));
    if ((threadIdx.x & 63) == 0) atomicMin(minb, lm);
}

__global__ void diag_abs(const float* __restrict__ Km, float* __restrict__ dbuf, int M) {
    int i = blockIdx.x * blockDim.x + threadIdx.x;
    if (i < M) dbuf[i] = fabsf(Km[(size_t)i * M + i]);
}

// fused normalized_kernel + hi/lo split (main path)
__global__ void normdiv_split(const float* __restrict__ Km, const float* __restrict__ dbuf,
                              const unsigned* __restrict__ minb,
                              ushort* __restrict__ kh, ushort* __restrict__ kl, int M) {
    int colc = blockIdx.x * blockDim.x + threadIdx.x;
    int row = blockIdx.y;
    float minv = __uint_as_float(minb[0]);
    float v = fabsf(Km[(size_t)row * M + colc]);
    if (v == 0.f) v = minv;
    float dj = dbuf[colc];
    if (dj == 0.f) dj = minv;
    float rr = v / dj;
    ushort h = bf16_rne(rr);
    float hf = __uint_as_float((unsigned)h << 16);
    size_t o = (size_t)row * M + colc;
    kh[o] = h;
    kl[o] = bf16_rne(rr - hf);
}

// in-place variant (fallback)
__global__ void normdiv(float* __restrict__ Km, const float* __restrict__ dbuf,
                        const unsigned* __restrict__ minb, int M) {
    int colc = blockIdx.x * blockDim.x + threadIdx.x;
    int row = blockIdx.y;
    float minv = __uint_as_float(minb[0]);
    float v = fabsf(Km[(size_t)row * M + colc]);
    if (v == 0.f) v = minv;
    float dj = dbuf[colc];
    if (dj == 0.f) dj = minv;
    Km[(size_t)row * M + colc] = v / dj;
}

__global__ void combine(float* __restrict__ out, const float* __restrict__ Bm) {
    __shared__ float t[32][33];
    int bx = blockIdx.x * 32;
    int by = blockIdx.y * 32;
    int tx = threadIdx.x & 31, ty = threadIdx.x >> 5;
#pragma unroll
    for (int k = 0; k < 32; k += 8)
        t[ty + k][tx] = Bm[(size_t)(bx + ty + k) * DSZ + by + tx];
    __syncthreads();
#pragma unroll
    for (int k = 0; k < 32; k += 8) {
        size_t idx = (size_t)(by + ty + k) * TSZ + bx + tx;
        out[idx] = 0.5f * (out[idx] + t[tx][ty + k]);
    }
}

// ============================================================================
extern "C" void kernel_launch(void* const* d_in, const int* in_sizes, int n_in,
                              void* d_out, int out_size, void* d_ws, size_t ws_size,
                              hipStream_t stream) {
    (void)in_sizes; (void)n_in; (void)out_size;
    const float* x      = (const float*)d_in[0];
    const int*   ei     = (const int*)d_in[1];
    const float* W1     = (const float*)d_in[2];
    const float* as1    = (const float*)d_in[3];
    const float* ad1    = (const float*)d_in[4];
    const float* b1     = (const float*)d_in[5];
    const float* W2     = (const float*)d_in[6];
    const float* as2    = (const float*)d_in[7];
    const float* ad2    = (const float*)d_in[8];
    const float* b2     = (const float*)d_in[9];
    const float* W3     = (const float*)d_in[10];
    const float* as3    = (const float*)d_in[11];
    const float* ad3    = (const float*)d_in[12];
    const float* b3     = (const float*)d_in[13];
    const float* W4     = (const float*)d_in[14];
    const float* as4    = (const float*)d_in[15];
    const float* ad4    = (const float*)d_in[16];
    const float* b4     = (const float*)d_in[17];
    const float* alpha1 = (const float*)d_in[18];
    const float* alpha2 = (const float*)d_in[19];
    const float* dsim   = (const float*)d_in[20];
    const float* tsim   = (const float*)d_in[21];
    float* out = (float*)d_out;

    // ---- workspace carve ----
    char* base = (char*)d_ws;
    size_t off = 0;
    auto carve = [&](size_t bytes) -> void* {
        void* p = base + off;
        off = (off + bytes + 255) & ~(size_t)255;
        return p;
    };
    float* Bmat  = (float*)base;  // [TSZ][DSZ], aliases front region (dead by final phase)
    int* col     = (int*)carve((size_t)NE_TOT * 4);
    int* cnt     = (int*)carve((NN + 1) * 4);
    int* row_ofs = (int*)carve((NN + 1) * 4);
    int* cursor  = (int*)carve(NN * 4);
    float* s_src = (float*)carve((size_t)NN * 4 * 4);
    float* s_dst = (float*)carve((size_t)NN * 4 * 4);
    float* z     = (float*)carve((size_t)NN * 256 * 4);
    float* H1    = (float*)carve((size_t)NN * 256 * 4);
    float* H2    = (float*)carve((size_t)NN * 256 * 4);
    float* H3    = (float*)carve((size_t)NN * 256 * 4);
    float* H4    = (float*)carve((size_t)NN * 128 * 4);
    float* Yn_fb = (float*)carve((size_t)TSZ * 256 * 4);  // fallback-only fp32 Yn
    size_t bspan = ((size_t)TSZ * DSZ * 4 + 255) & ~(size_t)255;
    if (off < bspan) off = bspan;  // keep always-live tail clear of Bmat alias
    float* rbD      = (float*)carve((size_t)4 * DSZ * 4);
    float* rbT      = (float*)carve((size_t)4 * TSZ * 4);
    float* md0D     = (float*)carve(256);
    float* md0T     = (float*)carve(256);
    unsigned* minb  = (unsigned*)carve(256);
    float* dbD      = (float*)carve(DSZ * 4);
    float* dbT      = (float*)carve(TSZ * 4);
    float* drug_k   = (float*)carve((size_t)DSZ * DSZ * 4);
    float* tgt_k    = (float*)carve((size_t)TSZ * TSZ * 4);
    // bf16x3 tier
    ushort* YdH  = (ushort*)carve((size_t)DSZ * LDCAT * 2);
    ushort* YdL  = (ushort*)carve((size_t)DSZ * LDCAT * 2);
    ushort* YtH  = (ushort*)carve((size_t)TSZ * LDCAT * 2);
    ushort* YtL  = (ushort*)carve((size_t)TSZ * LDCAT * 2);
    ushort* a1Th = (ushort*)carve((size_t)TSZ * DSZ * 2);
    ushort* a1Tl = (ushort*)carve((size_t)TSZ * DSZ * 2);
    ushort* a2Th = (ushort*)carve((size_t)DSZ * TSZ * 2);
    ushort* a2Tl = (ushort*)carve((size_t)DSZ * TSZ * 2);
    ushort* Hh   = (ushort*)carve((size_t)NN * 256 * 2);
    ushort* Hl   = (ushort*)carve((size_t)NN * 256 * 2);
    ushort* wTh  = (ushort*)carve((size_t)256 * 256 * 2);
    ushort* wTl  = (ushort*)carve((size_t)256 * 256 * 2);
    ushort* xh   = (ushort*)carve((size_t)NN * NN * 2);
    ushort* xl   = (ushort*)carve((size_t)NN * NN * 2);
    ushort* w1Th = (ushort*)carve((size_t)NN * 256 * 2);
    ushort* w1Tl = (ushort*)carve((size_t)NN * 256 * 2);
    const bool use_mfma = (off <= ws_size);  // ws_size call-invariant: graph-safe
    // dk/tk alias xh/xl (x splits dead after layer-1 GEMM; 84 MB <= 151 MB)
    ushort* dkh = xh;
    ushort* dkl = dkh + (size_t)DSZ * DSZ;
    ushort* tkh = dkl + (size_t)DSZ * DSZ;
    ushort* tkl = tkh + (size_t)TSZ * TSZ;

    // ---- CSR build ----
    hipMemsetAsync(cnt, 0, (NN + 1) * 4, stream);
    hist_kernel<<<(NE_TOT + 255) / 256, 256, 0, stream>>>(ei, cnt);
    scan_kernel<<<1, 1024, 0, stream>>>(cnt, row_ofs);
    copy_cursor<<<(NN + 255) / 256, 256, 0, stream>>>(row_ofs, cursor);
    scatter_kernel<<<(NE_TOT + 255) / 256, 256, 0, stream>>>(ei, cursor, col);

    const float PSv[4] = {1.0f, 0.5f, 0.333f, 0.25f};
    float* Hs[4] = {H1, H2, H3, H4};
    const int Fo[4] = {256, 256, 256, 128};

    if (use_mfma) {
        // ---- layer 1: split-K=8 MFMA ----
        split_rm<<<4096, 256, 0, stream>>>(x, xh, xl, (size_t)NN * NN / 4);
        split_T<<<dim3(256 / 32, NN / 32), 256, 0, stream>>>(W1, w1Th, w1Tl, NN, 256);
        hipMemsetAsync(z, 0, (size_t)NN * 256 * 4, stream);
        gemm_bt_x3<2><<<dim3(2, NN / 128, 8), 256, 0, stream>>>(xh, xl, w1Th, w1Tl, z,
                                                                NN, 256, NN);
        attn_scores<<<NN, 256, 0, stream>>>(z, as1, ad1, s_src, s_dst, 256, 64);
        gat_aggregate<256, 64><<<NN / 4, 256, 0, stream>>>(z, row_ofs, col, s_src, s_dst, b1, H1);

        // ---- layers 2-4: split-K=2 MFMA ----
        const float* Ws[3] = {W2, W3, W4};
        const float* ass[3] = {as2, as3, as4};
        const float* ads[3] = {ad2, ad3, ad4};
        const float* bs[3] = {b2, b3, b4};
        for (int l = 0; l < 3; l++) {
            int Nout = (l == 2) ? 128 : 256;
            split_rm<<<1024, 256, 0, stream>>>(Hs[l], Hh, Hl, (size_t)NN * 256 / 4);
            split_T<<<dim3(Nout / 32, 256 / 32), 256, 0, stream>>>(Ws[l], wTh, wTl, 256, Nout);
            hipMemsetAsync(z, 0, (size_t)NN * Nout * 4, stream);
            gemm_bt_x3<2><<<dim3(Nout / 128, NN / 128, 2), 256, 0, stream>>>(
                Hh, Hl, wTh, wTl, z, NN, Nout, 256);
            attn_scores<<<NN, 256, 0, stream>>>(z, ass[l], ads[l], s_src, s_dst, Nout, Nout / 4);
            if (l < 2)
                gat_aggregate<256, 64><<<NN / 4, 256, 0, stream>>>(z, row_ofs, col, s_src,
                                                                   s_dst, bs[l], Hs[l + 1]);
            else
                gat_aggregate<128, 32><<<NN / 4, 256, 0, stream>>>(z, row_ofs, col, s_src,
                                                                   s_dst, bs[l], Hs[l + 1]);
        }

        // ---- GIP normalize (hi/lo concat, fused md0 accumulation) + fused grams ----
        hipMemsetAsync(md0D, 0, 256, stream);
        hipMemsetAsync(md0T, 0, 256, stream);
        for (int l = 0; l < 4; l++) {
            gip_norm_split<<<DSZ, Fo[l], 0, stream>>>(Hs[l], YdH, YdL, rbD + l * DSZ,
                                                      md0D + l, 1.f / DSZ, Fo[l], l * 256);
            gip_norm_split<<<TSZ, Fo[l], 0, stream>>>(Hs[l] + (size_t)DSZ * Fo[l], YtH, YtL,
                                                      rbT + l * TSZ, md0T + l, 1.f / TSZ,
                                                      Fo[l], l * 256);
        }
        gram_fused<<<dim3(DSZ / 128, DSZ / 128), 256, 0, stream>>>(YdH, YdL, dsim, drug_k,
                                                                   rbD, md0D, DSZ);
        gram_fused<<<dim3(TSZ / 128, TSZ / 128), 256, 0, stream>>>(YtH, YtL, tsim, tgt_k,
                                                                   rbT, md0T, TSZ);

        // ---- normalized_kernel (fused hi/lo split) ----
        init_min<<<1, 64, 0, stream>>>(minb);
        min_nonzero<<<1024, 256, 0, stream>>>(drug_k, minb + 0, (size_t)DSZ * DSZ);
        diag_abs<<<(DSZ + 255) / 256, 256, 0, stream>>>(drug_k, dbD, DSZ);
        normdiv_split<<<dim3(DSZ / 256, DSZ), 256, 0, stream>>>(drug_k, dbD, minb + 0,
                                                                dkh, dkl, DSZ);
        min_nonzero<<<1024, 256, 0, stream>>>(tgt_k, minb + 1, (size_t)TSZ * TSZ);
        diag_abs<<<(TSZ + 255) / 256, 256, 0, stream>>>(tgt_k, dbT, TSZ);
        normdiv_split<<<dim3(TSZ / 256, TSZ), 256, 0, stream>>>(tgt_k, dbT, minb + 1,
                                                                tkh, tkl, TSZ);

        // ---- finals ----
        split_T<<<dim3(TSZ / 32, DSZ / 32), 256, 0, stream>>>(alpha1, a1Th, a1Tl, DSZ, TSZ);
        split_T<<<dim3(DSZ / 32, TSZ / 32), 256, 0, stream>>>(alpha2, a2Th, a2Tl, TSZ, DSZ);
        gemm_bt_x3<0><<<dim3(TSZ / 128, DSZ / 128), 256, 0, stream>>>(dkh, dkl, a1Th, a1Tl,
                                                                      out, DSZ, TSZ, DSZ);
        gemm_bt_x3<0><<<dim3(DSZ / 128, TSZ / 128), 256, 0, stream>>>(tkh, tkl, a2Th, a2Tl,
                                                                      Bmat, TSZ, DSZ, TSZ);
    } else {
        // ---- fallback: fp32 SIMT everywhere ----
        hipMemsetAsync(z, 0, (size_t)NN * 256 * 4, stream);
        gemm64<true><<<dim3(256 / 64, NN / 64, 8), 256, 0, stream>>>(x, W1, z, NN, 256, NN);
        attn_scores<<<NN, 256, 0, stream>>>(z, as1, ad1, s_src, s_dst, 256, 64);
        gat_aggregate<256, 64><<<NN / 4, 256, 0, stream>>>(z, row_ofs, col, s_src, s_dst, b1, H1);
        gemm64<false><<<dim3(256 / 64, NN / 64), 256, 0, stream>>>(H1, W2, z, NN, 256, 256);
        attn_scores<<<NN, 256, 0, stream>>>(z, as2, ad2, s_src, s_dst, 256, 64);
        gat_aggregate<256, 64><<<NN / 4, 256, 0, stream>>>(z, row_ofs, col, s_src, s_dst, b2, H2);
        gemm64<false><<<dim3(256 / 64, NN / 64), 256, 0, stream>>>(H2, W3, z, NN, 256, 256);
        attn_scores<<<NN, 256, 0, stream>>>(z, as3, ad3, s_src, s_dst, 256, 64);
        gat_aggregate<256, 64><<<NN / 4, 256, 0, stream>>>(z, row_ofs, col, s_src, s_dst, b3, H3);
        gemm64<false><<<dim3(128 / 64, NN / 64), 256, 0, stream>>>(H3, W4, z, NN, 128, 256);
        attn_scores<<<NN, 256, 0, stream>>>(z, as4, ad4, s_src, s_dst, 128, 32);
        gat_aggregate<128, 32><<<NN / 4, 256, 0, stream>>>(z, row_ofs, col, s_src, s_dst, b4, H4);

        scale_copy<<<4096, 256, 0, stream>>>(dsim, drug_k, 0.2f, (size_t)DSZ * DSZ);
        scale_copy<<<8192, 256, 0, stream>>>(tsim, tgt_k, 0.2f, (size_t)TSZ * TSZ);
        for (int l = 0; l < 4; l++) {
            gip_norm<<<DSZ, Fo[l], 0, stream>>>(Hs[l], Yn_fb, rbT, Fo[l]);
            mean_reduce<<<1, 1024, 0, stream>>>(rbT, md0T, DSZ);
            gram64<<<dim3(DSZ / 64, DSZ / 64), 256, 0, stream>>>(Yn_fb, drug_k, rbT, md0T,
                                                                 PSv[l], DSZ, Fo[l]);
            gip_norm<<<TSZ, Fo[l], 0, stream>>>(Hs[l] + (size_t)DSZ * Fo[l], Yn_fb, rbT, Fo[l]);
            mean_reduce<<<1, 1024, 0, stream>>>(rbT, md0T, TSZ);
            gram64<<<dim3(TSZ / 64, TSZ / 64), 256, 0, stream>>>(Yn_fb, tgt_k, rbT, md0T,
                                                                 PSv[l], TSZ, Fo[l]);
        }
        init_min<<<1, 64, 0, stream>>>(minb);
        min_nonzero<<<1024, 256, 0, stream>>>(drug_k, minb + 0, (size_t)DSZ * DSZ);
        diag_abs<<<(DSZ + 255) / 256, 256, 0, stream>>>(drug_k, dbD, DSZ);
        normdiv<<<dim3(DSZ / 256, DSZ), 256, 0, stream>>>(drug_k, dbD, minb + 0, DSZ);
        min_nonzero<<<1024, 256, 0, stream>>>(tgt_k, minb + 1, (size_t)TSZ * TSZ);
        diag_abs<<<(TSZ + 255) / 256, 256, 0, stream>>>(tgt_k, dbT, TSZ);
        normdiv<<<dim3(TSZ / 256, TSZ), 256, 0, stream>>>(tgt_k, dbT, minb + 1, TSZ);
        gemm64<false><<<dim3(TSZ / 64, DSZ / 64), 256, 0, stream>>>(drug_k, alpha1, out,
                                                                    DSZ, TSZ, DSZ);
        gemm64<false><<<dim3(DSZ / 64, TSZ / 64), 256, 0, stream>>>(tgt_k, alpha2, Bmat,
                                                                    TSZ, DSZ, TSZ);
    }
    combine<<<dim3(TSZ / 32, DSZ / 32), 256, 0, stream>>>(out, Bmat);
}

// Round 7
// 2178.656 us; speedup vs baseline: 1.0815x; 1.0815x over previous
//
#include <hip/hip_runtime.h>
#include <math.h>

#define NN 6144
#define DSZ 2048
#define TSZ 4096
#define NE 1048576
#define NE_TOT (NE + NN)
#define NEG_SLOPE 0.2f
#define GGAMMA 0.03125f
#define LDCAT 896  // concatenated K for fused gram: 256*3 + 128

typedef float floatx4 __attribute__((ext_vector_type(4)));
typedef __bf16 bf16x8 __attribute__((ext_vector_type(8)));

// ---------------- CSR build (counting sort by dst) ----------------
__global__ void hist_kernel(const int* __restrict__ ei, int* __restrict__ cnt) {
    int e = blockIdx.x * blockDim.x + threadIdx.x;
    if (e >= NE_TOT) return;
    int d = (e < NE) ? ei[NE + e] : (e - NE);
    atomicAdd(&cnt[d], 1);
}

__global__ void scan_kernel(const int* __restrict__ cnt, int* __restrict__ row_ofs) {
    __shared__ int part[1024];
    int t = threadIdx.x;
    int local[6];
    int s = 0;
#pragma unroll
    for (int i = 0; i < 6; i++) { local[i] = s; s += cnt[t * 6 + i]; }
    part[t] = s;
    __syncthreads();
    for (int off = 1; off < 1024; off <<= 1) {
        int v = (t >= off) ? part[t - off] : 0;
        __syncthreads();
        part[t] += v;
        __syncthreads();
    }
    int base = (t == 0) ? 0 : part[t - 1];
#pragma unroll
    for (int i = 0; i < 6; i++) row_ofs[t * 6 + i] = base + local[i];
    if (t == 1023) row_ofs[NN] = part[1023];
}

__global__ void copy_cursor(const int* __restrict__ row_ofs, int* __restrict__ cursor) {
    int i = blockIdx.x * blockDim.x + threadIdx.x;
    if (i < NN) cursor[i] = row_ofs[i];
}

__global__ void scatter_kernel(const int* __restrict__ ei, int* __restrict__ cursor,
                               int* __restrict__ col) {
    int e = blockIdx.x * blockDim.x + threadIdx.x;
    if (e >= NE_TOT) return;
    int s, d;
    if (e < NE) { s = ei[e]; d = ei[NE + e]; } else { s = e - NE; d = s; }
    int pos = atomicAdd(&cursor[d], 1);
    col[pos] = s;
}

// ---------------- generic fp32 GEMM (fallback only) ----------------
template <bool ATOMIC>
__global__ __launch_bounds__(256) void gemm64(const float* __restrict__ A,
                                              const float* __restrict__ B,
                                              float* __restrict__ C,
                                              int M, int N, int K) {
    __shared__ float As[16][68];
    __shared__ float Bs[16][68];
    const int tid = threadIdx.x;
    const int tn = tid & 15, tm = tid >> 4;
    const int bm = blockIdx.y * 64, bn = blockIdx.x * 64;
    const int ar = tid >> 2, ac = (tid & 3) * 4;
    const int br = tid >> 4, bc = (tid & 15) * 4;
    int kbeg = 0, kend = K;
    if constexpr (ATOMIC) {
        int klen = K / gridDim.z;
        kbeg = blockIdx.z * klen;
        kend = kbeg + klen;
    }
    const float* Ap = A + (size_t)(bm + ar) * K + ac;
    const float* Bp = B + (size_t)br * N + bn + bc;
    float acc[4][4] = {};
    for (int k0 = kbeg; k0 < kend; k0 += 16) {
        float4 av = *(const float4*)(Ap + k0);
        float4 bv = *(const float4*)(Bp + (size_t)k0 * N);
        As[ac + 0][ar] = av.x; As[ac + 1][ar] = av.y;
        As[ac + 2][ar] = av.z; As[ac + 3][ar] = av.w;
        *(float4*)&Bs[br][bc] = bv;
        __syncthreads();
#pragma unroll
        for (int k = 0; k < 16; k++) {
            float4 a4 = *(const float4*)&As[k][tm * 4];
            float4 b4 = *(const float4*)&Bs[k][tn * 4];
            float aa[4] = {a4.x, a4.y, a4.z, a4.w};
            float bb[4] = {b4.x, b4.y, b4.z, b4.w};
#pragma unroll
            for (int i = 0; i < 4; i++)
#pragma unroll
                for (int j = 0; j < 4; j++) acc[i][j] = fmaf(aa[i], bb[j], acc[i][j]);
        }
        __syncthreads();
    }
#pragma unroll
    for (int i = 0; i < 4; i++) {
        float* cp = C + (size_t)(bm + tm * 4 + i) * N + bn + tn * 4;
        if constexpr (ATOMIC) {
#pragma unroll
            for (int j = 0; j < 4; j++) atomicAdd(cp + j, acc[i][j]);
        } else {
            *(float4*)cp = make_float4(acc[i][0], acc[i][1], acc[i][2], acc[i][3]);
        }
    }
}

// ---------------- bf16 hi/lo split helpers ----------------
__device__ __forceinline__ ushort bf16_rne(float x) {
    unsigned u = __float_as_uint(x);
    unsigned r = (u + 0x7fffu + ((u >> 16) & 1u)) >> 16;
    return (ushort)r;
}

__global__ void split_rm(const float* __restrict__ in, ushort* __restrict__ hi,
                         ushort* __restrict__ lo, size_t n4) {
    for (size_t i = (size_t)blockIdx.x * blockDim.x + threadIdx.x; i < n4;
         i += (size_t)gridDim.x * blockDim.x) {
        float4 v = ((const float4*)in)[i];
        float vv[4] = {v.x, v.y, v.z, v.w};
        ushort h[4], l[4];
#pragma unroll
        for (int j = 0; j < 4; j++) {
            h[j] = bf16_rne(vv[j]);
            float hf = __uint_as_float((unsigned)h[j] << 16);
            l[j] = bf16_rne(vv[j] - hf);
        }
        ((ushort4*)hi)[i] = make_ushort4(h[0], h[1], h[2], h[3]);
        ((ushort4*)lo)[i] = make_ushort4(l[0], l[1], l[2], l[3]);
    }
}

// transpose + split: fp32 [R][C] -> hiT/loT bf16 [C][R]
__global__ void split_T(const float* __restrict__ in, ushort* __restrict__ hiT,
                        ushort* __restrict__ loT, int R, int C) {
    __shared__ float tile[32][33];
    int bx = blockIdx.x * 32, by = blockIdx.y * 32;
    int tx = threadIdx.x & 31, ty = threadIdx.x >> 5;  // 32x8
#pragma unroll
    for (int k = 0; k < 32; k += 8)
        tile[ty + k][tx] = in[(size_t)(by + ty + k) * C + bx + tx];
    __syncthreads();
#pragma unroll
    for (int k = 0; k < 32; k += 8) {
        float v = tile[tx][ty + k];
        ushort h = bf16_rne(v);
        float hf = __uint_as_float((unsigned)h << 16);
        ushort l = bf16_rne(v - hf);
        size_t o = (size_t)(bx + ty + k) * R + by + tx;
        hiT[o] = h;
        loT[o] = l;
    }
}

// ---------------- bf16x3 MFMA GEMM: C[M][N] = A[M][K] @ B[N][K]^T ----------------
// EPI=0: C = result. EPI=2: atomicAdd (split-K over gridDim.z).
__device__ __forceinline__ void gl_lds16(const void* g, void* l) {
    __builtin_amdgcn_global_load_lds(
        (const __attribute__((address_space(1))) unsigned int*)g,
        (__attribute__((address_space(3))) unsigned int*)l, 16, 0, 0);
}

template <int EPI>
__global__ __launch_bounds__(256) void gemm_bt_x3(
    const ushort* __restrict__ Ah, const ushort* __restrict__ Al,
    const ushort* __restrict__ Bh, const ushort* __restrict__ Bl,
    float* __restrict__ C, int M, int N, int K) {
    __shared__ ushort lds[4][4096];  // Ah,Al,Bh,Bl tiles: 128 rows x 32 bf16 (64 B/row)
    const int t = threadIdx.x;
    const int bm = blockIdx.y * 128, bn = blockIdx.x * 128;

    const int srow = t >> 2;
    const int scb = (t & 3) << 4;
    const int gcb = scb ^ (((srow >> 1) & 3) << 4);  // inverse swizzle on global source
    const int wid = t >> 6, lane = t & 63;

    int kbeg = 0, kend = K;
    if (gridDim.z > 1) {
        int klen = K / gridDim.z;
        kbeg = blockIdx.z * klen;
        kend = kbeg + klen;
    }

    const ushort* srcs[4] = {Ah, Al, Bh, Bl};
    const char* g[8];
    ushort* lp[8];
#pragma unroll
    for (int b = 0; b < 4; b++) {
        int rb = (b < 2) ? bm : bn;
#pragma unroll
        for (int i = 0; i < 2; i++) {
            g[b * 2 + i] = (const char*)srcs[b] + ((size_t)(rb + i * 64 + srow) * K) * 2 + gcb;
            lp[b * 2 + i] = &lds[b][i * 2048 + wid * 512];  // wave-uniform; HW adds lane*16B
        }
    }

    floatx4 acc[4][4];
#pragma unroll
    for (int m = 0; m < 4; m++)
#pragma unroll
        for (int n = 0; n < 4; n++) acc[m][n] = (floatx4){0.f, 0.f, 0.f, 0.f};

    const int wr = (wid >> 1) << 6, wc = (wid & 1) << 6;
    const int fr = lane & 15, kh = lane >> 4;
    const int cbf = (((kh << 4) ^ (((fr >> 1) & 3) << 4)) >> 1);

    for (int k0 = kbeg; k0 < kend; k0 += 32) {
#pragma unroll
        for (int q = 0; q < 8; q++) gl_lds16(g[q] + (size_t)k0 * 2, lp[q]);
        __syncthreads();
        bf16x8 bhf[4], blf[4];
#pragma unroll
        for (int n = 0; n < 4; n++) {
            int r = wc + n * 16 + fr;
            bhf[n] = *(const bf16x8*)&lds[2][r * 32 + cbf];
            blf[n] = *(const bf16x8*)&lds[3][r * 32 + cbf];
        }
#pragma unroll
        for (int m = 0; m < 4; m++) {
            int r = wr + m * 16 + fr;
            bf16x8 ahf = *(const bf16x8*)&lds[0][r * 32 + cbf];
            bf16x8 alf = *(const bf16x8*)&lds[1][r * 32 + cbf];
#pragma unroll
            for (int n = 0; n < 4; n++) {
                acc[m][n] = __builtin_amdgcn_mfma_f32_16x16x32_bf16(ahf, bhf[n], acc[m][n], 0, 0, 0);
                acc[m][n] = __builtin_amdgcn_mfma_f32_16x16x32_bf16(ahf, blf[n], acc[m][n], 0, 0, 0);
                acc[m][n] = __builtin_amdgcn_mfma_f32_16x16x32_bf16(alf, bhf[n], acc[m][n], 0, 0, 0);
            }
        }
        __syncthreads();
    }

#pragma unroll
    for (int m = 0; m < 4; m++) {
#pragma unroll
        for (int n = 0; n < 4; n++) {
#pragma unroll
            for (int r = 0; r < 4; r++) {
                int gr = bm + wr + m * 16 + kh * 4 + r;  // C/D: row=(lane>>4)*4+reg
                int gc = bn + wc + n * 16 + fr;          //      col=lane&15
                size_t idx = (size_t)gr * N + gc;
                if constexpr (EPI == 0) C[idx] = acc[m][n][r];
                else atomicAdd(&C[idx], acc[m][n][r]);
            }
        }
    }
}

// ---------------- fused finals: out = 0.5*(dk@a1 + (tk@a2)^T) ----------------
// out[i][j] = 0.5*( sum_k dk[i,k]*a1T[j,k]  +  sum_k a2T[i,k]*tk[j,k] )
// (single-buffer structure; 84-VGPR class -> 5 blocks/CU implicit overlap)
__global__ __launch_bounds__(256) void final_fused(
    const ushort* __restrict__ dkh, const ushort* __restrict__ dkl,
    const ushort* __restrict__ a1h, const ushort* __restrict__ a1l,
    const ushort* __restrict__ a2h, const ushort* __restrict__ a2l,
    const ushort* __restrict__ tkh, const ushort* __restrict__ tkl,
    float* __restrict__ out) {
    __shared__ ushort lds[4][4096];
    const int t = threadIdx.x;
    const int bm = blockIdx.y * 128, bn = blockIdx.x * 128;  // i-block (DSZ), j-block (TSZ)
    const int srow = t >> 2;
    const int scb = (t & 3) << 4;
    const int gcb = scb ^ (((srow >> 1) & 3) << 4);
    const int wid = t >> 6, lane = t & 63;
    const int wr = (wid >> 1) << 6, wc = (wid & 1) << 6;
    const int fr = lane & 15, kh = lane >> 4;
    const int cbf = (((kh << 4) ^ (((fr >> 1) & 3) << 4)) >> 1);

    ushort* lp[8];
#pragma unroll
    for (int b = 0; b < 4; b++)
#pragma unroll
        for (int i = 0; i < 2; i++)
            lp[b * 2 + i] = &lds[b][i * 2048 + wid * 512];

    floatx4 acc[4][4];
#pragma unroll
    for (int m = 0; m < 4; m++)
#pragma unroll
        for (int n = 0; n < 4; n++) acc[m][n] = (floatx4){0.f, 0.f, 0.f, 0.f};

#pragma unroll 1
    for (int phase = 0; phase < 2; phase++) {
        const int K = (phase == 0) ? DSZ : TSZ;
        const ushort* srcs[4];
        if (phase == 0) { srcs[0] = dkh; srcs[1] = dkl; srcs[2] = a1h; srcs[3] = a1l; }
        else            { srcs[0] = a2h; srcs[1] = a2l; srcs[2] = tkh; srcs[3] = tkl; }
        const char* g[8];
#pragma unroll
        for (int b = 0; b < 4; b++) {
            int rb = (b < 2) ? bm : bn;
#pragma unroll
            for (int i = 0; i < 2; i++)
                g[b * 2 + i] =
                    (const char*)srcs[b] + ((size_t)(rb + i * 64 + srow) * K) * 2 + gcb;
        }
#pragma unroll 1
        for (int k0 = 0; k0 < K; k0 += 32) {
#pragma unroll
            for (int q = 0; q < 8; q++) gl_lds16(g[q] + (size_t)k0 * 2, lp[q]);
            __syncthreads();
            bf16x8 bhf[4], blf[4];
#pragma unroll
            for (int n = 0; n < 4; n++) {
                int r = wc + n * 16 + fr;
                bhf[n] = *(const bf16x8*)&lds[2][r * 32 + cbf];
                blf[n] = *(const bf16x8*)&lds[3][r * 32 + cbf];
            }
#pragma unroll
            for (int m = 0; m < 4; m++) {
                int r = wr + m * 16 + fr;
                bf16x8 ahf = *(const bf16x8*)&lds[0][r * 32 + cbf];
                bf16x8 alf = *(const bf16x8*)&lds[1][r * 32 + cbf];
#pragma unroll
                for (int n = 0; n < 4; n++) {
                    acc[m][n] = __builtin_amdgcn_mfma_f32_16x16x32_bf16(ahf, bhf[n], acc[m][n], 0, 0, 0);
                    acc[m][n] = __builtin_amdgcn_mfma_f32_16x16x32_bf16(ahf, blf[n], acc[m][n], 0, 0, 0);
                    acc[m][n] = __builtin_amdgcn_mfma_f32_16x16x32_bf16(alf, bhf[n], acc[m][n], 0, 0, 0);
                }
            }
            __syncthreads();
        }
    }

#pragma unroll
    for (int m = 0; m < 4; m++) {
#pragma unroll
        for (int n = 0; n < 4; n++) {
#pragma unroll
            for (int r = 0; r < 4; r++) {
                int gr = bm + wr + m * 16 + kh * 4 + r;
                int gc = bn + wc + n * 16 + fr;
                out[(size_t)gr * TSZ + gc] = 0.5f * acc[m][n][r];
            }
        }
    }
}

// ---------------- fused 4-layer GIP gram, 2-phase pipelined ----------------
// Kout = 0.2*sim + sum_l p_l*exp(-(ri+rj-2*G_l)*g/md0_l)
// 2-phase: stage step t+1 into buf^1 BEFORE computing step t on buf; one barrier
// per step (its implicit vmcnt(0) drains next-tile loads under this tile's MFMAs).
__global__ __launch_bounds__(256) void gram_fused(
    const ushort* __restrict__ Yh, const ushort* __restrict__ Yl,
    const float* __restrict__ sim, float* __restrict__ Kout,
    const float* __restrict__ rbufs,  // [4][M]
    const float* __restrict__ md0s,   // [4]
    int M) {
    __shared__ ushort lds[2][4][4096];  // 64 KB: 2 phases x {Ah,Al,Bh,Bl}
    const int t = threadIdx.x;
    const int bm = blockIdx.y * 128, bn = blockIdx.x * 128;
    const int srow = t >> 2;
    const int scb = (t & 3) << 4;
    const int gcb = scb ^ (((srow >> 1) & 3) << 4);
    const int wid = t >> 6, lane = t & 63;

    const ushort* srcs[4] = {Yh, Yl, Yh, Yl};
    const char* g[8];
    int lofs[8];  // ushort offset within one phase buffer
#pragma unroll
    for (int b = 0; b < 4; b++) {
        int rb = (b < 2) ? bm : bn;
#pragma unroll
        for (int i = 0; i < 2; i++) {
            g[b * 2 + i] = (const char*)srcs[b] + ((size_t)(rb + i * 64 + srow) * LDCAT) * 2 + gcb;
            lofs[b * 2 + i] = b * 4096 + i * 2048 + wid * 512;
        }
    }
    ushort* lbase = &lds[0][0][0];

    const int wr = (wid >> 1) << 6, wc = (wid & 1) << 6;
    const int fr = lane & 15, kh = lane >> 4;
    const int cbf = (((kh << 4) ^ (((fr >> 1) & 3) << 4)) >> 1);

    floatx4 acc[4][4], epi[4][4];
#pragma unroll
    for (int m = 0; m < 4; m++)
#pragma unroll
        for (int n = 0; n < 4; n++) {
            acc[m][n] = (floatx4){0.f, 0.f, 0.f, 0.f};
            epi[m][n] = (floatx4){0.f, 0.f, 0.f, 0.f};
        }

    // prologue: stage step 0 into phase 0
#pragma unroll
    for (int q = 0; q < 8; q++) gl_lds16(g[q], lbase + lofs[q]);
    __syncthreads();

    int cur = 0, l = 0;
#pragma unroll 1
    for (int step = 0; step < 28; step++) {
        // issue next-tile loads into the other phase buffer (overlaps with MFMA below)
        if (step + 1 < 28) {
            int kn = (step + 1) * 32;
            ushort* nb = lbase + (cur ^ 1) * 16384;
#pragma unroll
            for (int q = 0; q < 8; q++) gl_lds16(g[q] + (size_t)kn * 2, nb + lofs[q]);
        }
        const ushort* cb = lbase + cur * 16384;
        bf16x8 bhf[4], blf[4];
#pragma unroll
        for (int n = 0; n < 4; n++) {
            int r = wc + n * 16 + fr;
            bhf[n] = *(const bf16x8*)&cb[2 * 4096 + r * 32 + cbf];
            blf[n] = *(const bf16x8*)&cb[3 * 4096 + r * 32 + cbf];
        }
#pragma unroll
        for (int m = 0; m < 4; m++) {
            int r = wr + m * 16 + fr;
            bf16x8 ahf = *(const bf16x8*)&cb[0 * 4096 + r * 32 + cbf];
            bf16x8 alf = *(const bf16x8*)&cb[1 * 4096 + r * 32 + cbf];
#pragma unroll
            for (int n = 0; n < 4; n++) {
                acc[m][n] = __builtin_amdgcn_mfma_f32_16x16x32_bf16(ahf, bhf[n], acc[m][n], 0, 0, 0);
                acc[m][n] = __builtin_amdgcn_mfma_f32_16x16x32_bf16(ahf, blf[n], acc[m][n], 0, 0, 0);
                acc[m][n] = __builtin_amdgcn_mfma_f32_16x16x32_bf16(alf, bhf[n], acc[m][n], 0, 0, 0);
            }
        }
        // layer boundary: fold acc into epi via GIP exp, reset acc
        if (step == 7 || step == 15 || step == 23 || step == 27) {
            float sc = GGAMMA / md0s[l];
            float pl = (l == 0) ? 1.0f : (l == 1) ? 0.5f : (l == 2) ? 0.333f : 0.25f;
            const float* rb_ = rbufs + (size_t)l * M;
#pragma unroll
            for (int m = 0; m < 4; m++) {
#pragma unroll
                for (int r = 0; r < 4; r++) {
                    float ri = rb_[bm + wr + m * 16 + kh * 4 + r];
#pragma unroll
                    for (int n = 0; n < 4; n++) {
                        float rj = rb_[bn + wc + n * 16 + fr];
                        epi[m][n][r] += pl * expf(-(ri + rj - 2.f * acc[m][n][r]) * sc);
                        acc[m][n][r] = 0.f;
                    }
                }
            }
            l++;
        }
        __syncthreads();  // implicit vmcnt(0): next-phase loads complete here
        cur ^= 1;
    }

#pragma unroll
    for (int m = 0; m < 4; m++) {
#pragma unroll
        for (int n = 0; n < 4; n++) {
#pragma unroll
            for (int r = 0; r < 4; r++) {
                int gr = bm + wr + m * 16 + kh * 4 + r;
                int gc = bn + wc + n * 16 + fr;
                size_t idx = (size_t)gr * M + gc;
                Kout[idx] = 0.2f * sim[idx] + epi[m][n][r];
            }
        }
    }
}

// ---------------- per-node attention scalars ----------------
__global__ void attn_scores(const float* __restrict__ z, const float* __restrict__ a_src,
                            const float* __restrict__ a_dst, float* __restrict__ s_src,
                            float* __restrict__ s_dst, int Fout, int F) {
    int n = blockIdx.x, t = threadIdx.x;
    __shared__ float r1[256], r2[256];
    float v = (t < Fout) ? z[(size_t)n * Fout + t] : 0.f;
    r1[t] = (t < Fout) ? v * a_src[t] : 0.f;
    r2[t] = (t < Fout) ? v * a_dst[t] : 0.f;
    __syncthreads();
    for (int off = F >> 1; off > 0; off >>= 1) {
        if ((t & (F - 1)) < off) { r1[t] += r1[t + off]; r2[t] += r2[t + off]; }
        __syncthreads();
    }
    if (t < Fout && (t & (F - 1)) == 0) {
        int h = t / F;
        s_src[n * 4 + h] = r1[t];
        s_dst[n * 4 + h] = r2[t];
    }
}

// ---------------- GAT aggregate ----------------
template <int FOUT, int F>
__global__ __launch_bounds__(256) void gat_aggregate(
    const float* __restrict__ z, const int* __restrict__ row_ofs,
    const int* __restrict__ col, const float* __restrict__ s_src,
    const float* __restrict__ s_dst, const float* __restrict__ bias,
    float* __restrict__ H) {
    constexpr int VPL = FOUT / 64;
    int wave = threadIdx.x >> 6, lane = threadIdx.x & 63;
    int n = blockIdx.x * 4 + wave;
    int beg = row_ofs[n], end = row_ofs[n + 1];
    int f0 = lane * VPL;
    int h = f0 / F;
    float4 sd4 = *(const float4*)&s_dst[n * 4];
    float mx[4] = {-__builtin_inff(), -__builtin_inff(), -__builtin_inff(), -__builtin_inff()};
    for (int e = beg + lane; e < end; e += 64) {
        int s = col[e];
        float4 ss = *(const float4*)&s_src[s * 4];
        float l0 = ss.x + sd4.x; l0 = l0 > 0.f ? l0 : NEG_SLOPE * l0;
        float l1 = ss.y + sd4.y; l1 = l1 > 0.f ? l1 : NEG_SLOPE * l1;
        float l2 = ss.z + sd4.z; l2 = l2 > 0.f ? l2 : NEG_SLOPE * l2;
        float l3 = ss.w + sd4.w; l3 = l3 > 0.f ? l3 : NEG_SLOPE * l3;
        mx[0] = fmaxf(mx[0], l0); mx[1] = fmaxf(mx[1], l1);
        mx[2] = fmaxf(mx[2], l2); mx[3] = fmaxf(mx[3], l3);
    }
#pragma unroll
    for (int off = 32; off > 0; off >>= 1) {
#pragma unroll
        for (int hh = 0; hh < 4; hh++) mx[hh] = fmaxf(mx[hh], __shfl_xor(mx[hh], off));
    }
    float mh = (h == 0) ? mx[0] : (h == 1) ? mx[1] : (h == 2) ? mx[2] : mx[3];
    float sdh = (h == 0) ? sd4.x : (h == 1) ? sd4.y : (h == 2) ? sd4.z : sd4.w;
    float acc[VPL] = {};
    float wsum = 0.f;
    for (int e = beg; e < end; e++) {
        int s = col[e];
        float l = s_src[s * 4 + h] + sdh;
        l = l > 0.f ? l : NEG_SLOPE * l;
        float w = expf(l - mh);
        wsum += w;
        const float* zp = z + (size_t)s * FOUT + f0;
        if constexpr (VPL == 4) {
            float4 zv = *(const float4*)zp;
            acc[0] = fmaf(w, zv.x, acc[0]); acc[1] = fmaf(w, zv.y, acc[1]);
            acc[2] = fmaf(w, zv.z, acc[2]); acc[3] = fmaf(w, zv.w, acc[3]);
        } else {
            float2 zv = *(const float2*)zp;
            acc[0] = fmaf(w, zv.x, acc[0]); acc[1] = fmaf(w, zv.y, acc[1]);
        }
    }
    float inv = 1.f / wsum;
#pragma unroll
    for (int i = 0; i < VPL; i++) {
        float o = acc[i] * inv + bias[f0 + i];
        H[(size_t)n * FOUT + f0 + i] = o > 0.f ? o : 0.f;
    }
}

// ---------------- GIP row normalize -> hi/lo bf16 concat + row sq-norm + md0 atomic ----
__global__ void gip_norm_split(const float* __restrict__ Y, ushort* __restrict__ Yh,
                               ushort* __restrict__ Yl, float* __restrict__ r,
                               float* __restrict__ md0p, float invM,
                               int Fout, int kofs) {
    int row = blockIdx.x, t = threadIdx.x;  // blockDim.x == Fout
    __shared__ float s1[256], s2[256];
    float v = Y[(size_t)row * Fout + t];
    s1[t] = v; s2[t] = v;
    __syncthreads();
    for (int off = blockDim.x >> 1; off > 0; off >>= 1) {
        if (t < off) {
            s1[t] = fminf(s1[t], s1[t + off]);
            s2[t] = fmaxf(s2[t], s2[t + off]);
        }
        __syncthreads();
    }
    float mn = s1[0], mx = s2[0];
    float rng = mx - mn;
    if (rng == 0.f) rng = 1.f;
    float yn = (v - mn) / rng;
    ushort h = bf16_rne(yn);
    float hf = __uint_as_float((unsigned)h << 16);
    ushort lo = bf16_rne(yn - hf);
    size_t o = (size_t)row * LDCAT + kofs + t;
    Yh[o] = h;
    Yl[o] = lo;
    __syncthreads();
    s1[t] = yn * yn;
    __syncthreads();
    for (int off = blockDim.x >> 1; off > 0; off >>= 1) {
        if (t < off) s1[t] += s1[t + off];
        __syncthreads();
    }
    if (t == 0) {
        r[row] = s1[0];
        atomicAdd(md0p, s1[0] * invM);
    }
}

// fp32 variant (fallback path)
__global__ void gip_norm(const float* __restrict__ Y, float* __restrict__ Yn,
                         float* __restrict__ r, int Fout) {
    int row = blockIdx.x, t = threadIdx.x;
    __shared__ float s1[256], s2[256];
    float v = Y[(size_t)row * Fout + t];
    s1[t] = v; s2[t] = v;
    __syncthreads();
    for (int off = blockDim.x >> 1; off > 0; off >>= 1) {
        if (t < off) {
            s1[t] = fminf(s1[t], s1[t + off]);
            s2[t] = fmaxf(s2[t], s2[t + off]);
        }
        __syncthreads();
    }
    float mn = s1[0], mx = s2[0];
    float rng = mx - mn;
    if (rng == 0.f) rng = 1.f;
    float yn = (v - mn) / rng;
    Yn[(size_t)row * Fout + t] = yn;
    __syncthreads();
    s1[t] = yn * yn;
    __syncthreads();
    for (int off = blockDim.x >> 1; off > 0; off >>= 1) {
        if (t < off) s1[t] += s1[t + off];
        __syncthreads();
    }
    if (t == 0) r[row] = s1[0];
}

__global__ void mean_reduce(const float* __restrict__ r, float* __restrict__ md0, int M) {
    __shared__ float s[1024];
    int t = threadIdx.x;
    float acc = 0.f;
    for (int i = t; i < M; i += 1024) acc += r[i];
    s[t] = acc;
    __syncthreads();
    for (int off = 512; off > 0; off >>= 1) {
        if (t < off) s[t] += s[t + off];
        __syncthreads();
    }
    if (t == 0) md0[0] = s[0] / (float)M;
}

// ---------------- fp32 gram (fallback only) ----------------
__global__ __launch_bounds__(256) void gram64(const float* __restrict__ Y,
                                              float* __restrict__ Kacc,
                                              const float* __restrict__ rbuf,
                                              const float* __restrict__ md0buf,
                                              float p, int M, int K) {
    __shared__ float As[16][68];
    __shared__ float Bs[16][68];
    const int tid = threadIdx.x;
    const int tn = tid & 15, tm = tid >> 4;
    const int bm = blockIdx.y * 64, bn = blockIdx.x * 64;
    const int ar = tid >> 2, ac = (tid & 3) * 4;
    const float* Ap = Y + (size_t)(bm + ar) * K + ac;
    const float* Bp = Y + (size_t)(bn + ar) * K + ac;
    float acc[4][4] = {};
    for (int k0 = 0; k0 < K; k0 += 16) {
        float4 av = *(const float4*)(Ap + k0);
        float4 bv = *(const float4*)(Bp + k0);
        As[ac + 0][ar] = av.x; As[ac + 1][ar] = av.y;
        As[ac + 2][ar] = av.z; As[ac + 3][ar] = av.w;
        Bs[ac + 0][ar] = bv.x; Bs[ac + 1][ar] = bv.y;
        Bs[ac + 2][ar] = bv.z; Bs[ac + 3][ar] = bv.w;
        __syncthreads();
#pragma unroll
        for (int k = 0; k < 16; k++) {
            float4 a4 = *(const float4*)&As[k][tm * 4];
            float4 b4 = *(const float4*)&Bs[k][tn * 4];
            float aa[4] = {a4.x, a4.y, a4.z, a4.w};
            float bb[4] = {b4.x, b4.y, b4.z, b4.w};
#pragma unroll
            for (int i = 0; i < 4; i++)
#pragma unroll
                for (int j = 0; j < 4; j++) acc[i][j] = fmaf(aa[i], bb[j], acc[i][j]);
        }
        __syncthreads();
    }
    float sc = GGAMMA / md0buf[0];
    float ri[4], rj[4];
#pragma unroll
    for (int i = 0; i < 4; i++) ri[i] = rbuf[bm + tm * 4 + i];
#pragma unroll
    for (int j = 0; j < 4; j++) rj[j] = rbuf[bn + tn * 4 + j];
#pragma unroll
    for (int i = 0; i < 4; i++) {
#pragma unroll
        for (int j = 0; j < 4; j++) {
            float val = p * expf(-(ri[i] + rj[j] - 2.f * acc[i][j]) * sc);
            size_t idx = (size_t)(bm + tm * 4 + i) * M + bn + tn * 4 + j;
            Kacc[idx] += val;
        }
    }
}

// ---------------- misc elementwise ----------------
__global__ void scale_copy(const float* __restrict__ src, float* __restrict__ dst,
                           float p, size_t n) {
    for (size_t i = (size_t)blockIdx.x * blockDim.x + threadIdx.x; i < n;
         i += (size_t)gridDim.x * blockDim.x)
        dst[i] = p * src[i];
}

__global__ void init_min(unsigned* minb) {
    if (threadIdx.x == 0 && blockIdx.x == 0) { minb[0] = 0x7f800000u; minb[1] = 0x7f800000u; }
}

__global__ void min_nonzero(const float* __restrict__ Km, unsigned* __restrict__ minb,
                            size_t total) {
    unsigned lm = 0x7f800000u;
    for (size_t i = (size_t)blockIdx.x * blockDim.x + threadIdx.x; i < total;
         i += (size_t)gridDim.x * blockDim.x) {
        float v = fabsf(Km[i]);
        if (v != 0.f) lm = min(lm, __float_as_uint(v));
    }
#pragma unroll
    for (int off = 32; off > 0; off >>= 1)
        lm = min(lm, (unsigned)__shfl_xor((int)lm, off));
    if ((threadIdx.x & 63) == 0) atomicMin(minb, lm);
}

__global__ void diag_abs(const float* __restrict__ Km, float* __restrict__ dbuf, int M) {
    int i = blockIdx.x * blockDim.x + threadIdx.x;
    if (i < M) dbuf[i] = fabsf(Km[(size_t)i * M + i]);
}

// fused normalized_kernel + hi/lo split (main path)
__global__ void normdiv_split(const float* __restrict__ Km, const float* __restrict__ dbuf,
                              const unsigned* __restrict__ minb,
                              ushort* __restrict__ kh, ushort* __restrict__ kl, int M) {
    int colc = blockIdx.x * blockDim.x + threadIdx.x;
    int row = blockIdx.y;
    float minv = __uint_as_float(minb[0]);
    float v = fabsf(Km[(size_t)row * M + colc]);
    if (v == 0.f) v = minv;
    float dj = dbuf[colc];
    if (dj == 0.f) dj = minv;
    float rr = v / dj;
    ushort h = bf16_rne(rr);
    float hf = __uint_as_float((unsigned)h << 16);
    size_t o = (size_t)row * M + colc;
    kh[o] = h;
    kl[o] = bf16_rne(rr - hf);
}

// in-place variant (fallback)
__global__ void normdiv(float* __restrict__ Km, const float* __restrict__ dbuf,
                        const unsigned* __restrict__ minb, int M) {
    int colc = blockIdx.x * blockDim.x + threadIdx.x;
    int row = blockIdx.y;
    float minv = __uint_as_float(minb[0]);
    float v = fabsf(Km[(size_t)row * M + colc]);
    if (v == 0.f) v = minv;
    float dj = dbuf[colc];
    if (dj == 0.f) dj = minv;
    Km[(size_t)row * M + colc] = v / dj;
}

__global__ void combine(float* __restrict__ out, const float* __restrict__ Bm) {
    __shared__ float t[32][33];
    int bx = blockIdx.x * 32;
    int by = blockIdx.y * 32;
    int tx = threadIdx.x & 31, ty = threadIdx.x >> 5;
#pragma unroll
    for (int k = 0; k < 32; k += 8)
        t[ty + k][tx] = Bm[(size_t)(bx + ty + k) * DSZ + by + tx];
    __syncthreads();
#pragma unroll
    for (int k = 0; k < 32; k += 8) {
        size_t idx = (size_t)(by + ty + k) * TSZ + bx + tx;
        out[idx] = 0.5f * (out[idx] + t[tx][ty + k]);
    }
}

// ============================================================================
extern "C" void kernel_launch(void* const* d_in, const int* in_sizes, int n_in,
                              void* d_out, int out_size, void* d_ws, size_t ws_size,
                              hipStream_t stream) {
    (void)in_sizes; (void)n_in; (void)out_size;
    const float* x      = (const float*)d_in[0];
    const int*   ei     = (const int*)d_in[1];
    const float* W1     = (const float*)d_in[2];
    const float* as1    = (const float*)d_in[3];
    const float* ad1    = (const float*)d_in[4];
    const float* b1     = (const float*)d_in[5];
    const float* W2     = (const float*)d_in[6];
    const float* as2    = (const float*)d_in[7];
    const float* ad2    = (const float*)d_in[8];
    const float* b2     = (const float*)d_in[9];
    const float* W3     = (const float*)d_in[10];
    const float* as3    = (const float*)d_in[11];
    const float* ad3    = (const float*)d_in[12];
    const float* b3     = (const float*)d_in[13];
    const float* W4     = (const float*)d_in[14];
    const float* as4    = (const float*)d_in[15];
    const float* ad4    = (const float*)d_in[16];
    const float* b4     = (const float*)d_in[17];
    const float* alpha1 = (const float*)d_in[18];
    const float* alpha2 = (const float*)d_in[19];
    const float* dsim   = (const float*)d_in[20];
    const float* tsim   = (const float*)d_in[21];
    float* out = (float*)d_out;

    // ---- workspace carve ----
    char* base = (char*)d_ws;
    size_t off = 0;
    auto carve = [&](size_t bytes) -> void* {
        void* p = base + off;
        off = (off + bytes + 255) & ~(size_t)255;
        return p;
    };
    float* Bmat  = (float*)base;  // [TSZ][DSZ], fallback-only (aliases front region)
    int* col     = (int*)carve((size_t)NE_TOT * 4);
    int* cnt     = (int*)carve((NN + 1) * 4);
    int* row_ofs = (int*)carve((NN + 1) * 4);
    int* cursor  = (int*)carve(NN * 4);
    float* s_src = (float*)carve((size_t)NN * 4 * 4);
    float* s_dst = (float*)carve((size_t)NN * 4 * 4);
    float* z     = (float*)carve((size_t)NN * 256 * 4);
    float* H1    = (float*)carve((size_t)NN * 256 * 4);
    float* H2    = (float*)carve((size_t)NN * 256 * 4);
    float* H3    = (float*)carve((size_t)NN * 256 * 4);
    float* H4    = (float*)carve((size_t)NN * 128 * 4);
    float* Yn_fb = (float*)carve((size_t)TSZ * 256 * 4);  // fallback-only fp32 Yn
    size_t bspan = ((size_t)TSZ * DSZ * 4 + 255) & ~(size_t)255;
    if (off < bspan) off = bspan;  // keep always-live tail clear of Bmat alias
    float* rbD      = (float*)carve((size_t)4 * DSZ * 4);
    float* rbT      = (float*)carve((size_t)4 * TSZ * 4);
    float* md0D     = (float*)carve(256);
    float* md0T     = (float*)carve(256);
    unsigned* minb  = (unsigned*)carve(256);
    float* dbD      = (float*)carve(DSZ * 4);
    float* dbT      = (float*)carve(TSZ * 4);
    float* drug_k   = (float*)carve((size_t)DSZ * DSZ * 4);
    float* tgt_k    = (float*)carve((size_t)TSZ * TSZ * 4);
    // bf16x3 tier
    ushort* YdH  = (ushort*)carve((size_t)DSZ * LDCAT * 2);
    ushort* YdL  = (ushort*)carve((size_t)DSZ * LDCAT * 2);
    ushort* YtH  = (ushort*)carve((size_t)TSZ * LDCAT * 2);
    ushort* YtL  = (ushort*)carve((size_t)TSZ * LDCAT * 2);
    ushort* a1Th = (ushort*)carve((size_t)TSZ * DSZ * 2);
    ushort* a1Tl = (ushort*)carve((size_t)TSZ * DSZ * 2);
    ushort* a2Th = (ushort*)carve((size_t)DSZ * TSZ * 2);
    ushort* a2Tl = (ushort*)carve((size_t)DSZ * TSZ * 2);
    ushort* Hh   = (ushort*)carve((size_t)NN * 256 * 2);
    ushort* Hl   = (ushort*)carve((size_t)NN * 256 * 2);
    ushort* wTh  = (ushort*)carve((size_t)256 * 256 * 2);
    ushort* wTl  = (ushort*)carve((size_t)256 * 256 * 2);
    ushort* xh   = (ushort*)carve((size_t)NN * NN * 2);
    ushort* xl   = (ushort*)carve((size_t)NN * NN * 2);
    ushort* w1Th = (ushort*)carve((size_t)NN * 256 * 2);
    ushort* w1Tl = (ushort*)carve((size_t)NN * 256 * 2);
    const bool use_mfma = (off <= ws_size);  // ws_size call-invariant: graph-safe
    // dk/tk alias xh/xl (x splits dead after layer-1 GEMM; 84 MB <= 151 MB)
    ushort* dkh = xh;
    ushort* dkl = dkh + (size_t)DSZ * DSZ;
    ushort* tkh = dkl + (size_t)DSZ * DSZ;
    ushort* tkl = tkh + (size_t)TSZ * TSZ;

    // ---- CSR build ----
    hipMemsetAsync(cnt, 0, (NN + 1) * 4, stream);
    hist_kernel<<<(NE_TOT + 255) / 256, 256, 0, stream>>>(ei, cnt);
    scan_kernel<<<1, 1024, 0, stream>>>(cnt, row_ofs);
    copy_cursor<<<(NN + 255) / 256, 256, 0, stream>>>(row_ofs, cursor);
    scatter_kernel<<<(NE_TOT + 255) / 256, 256, 0, stream>>>(ei, cursor, col);

    const float PSv[4] = {1.0f, 0.5f, 0.333f, 0.25f};
    float* Hs[4] = {H1, H2, H3, H4};
    const int Fo[4] = {256, 256, 256, 128};

    if (use_mfma) {
        // ---- layer 1: split-K=8 MFMA ----
        split_rm<<<4096, 256, 0, stream>>>(x, xh, xl, (size_t)NN * NN / 4);
        split_T<<<dim3(256 / 32, NN / 32), 256, 0, stream>>>(W1, w1Th, w1Tl, NN, 256);
        hipMemsetAsync(z, 0, (size_t)NN * 256 * 4, stream);
        gemm_bt_x3<2><<<dim3(2, NN / 128, 8), 256, 0, stream>>>(xh, xl, w1Th, w1Tl, z,
                                                                NN, 256, NN);
        attn_scores<<<NN, 256, 0, stream>>>(z, as1, ad1, s_src, s_dst, 256, 64);
        gat_aggregate<256, 64><<<NN / 4, 256, 0, stream>>>(z, row_ofs, col, s_src, s_dst, b1, H1);

        // ---- layers 2-4: split-K=2 MFMA ----
        const float* Ws[3] = {W2, W3, W4};
        const float* ass[3] = {as2, as3, as4};
        const float* ads[3] = {ad2, ad3, ad4};
        const float* bs[3] = {b2, b3, b4};
        for (int l = 0; l < 3; l++) {
            int Nout = (l == 2) ? 128 : 256;
            split_rm<<<1024, 256, 0, stream>>>(Hs[l], Hh, Hl, (size_t)NN * 256 / 4);
            split_T<<<dim3(Nout / 32, 256 / 32), 256, 0, stream>>>(Ws[l], wTh, wTl, 256, Nout);
            hipMemsetAsync(z, 0, (size_t)NN * Nout * 4, stream);
            gemm_bt_x3<2><<<dim3(Nout / 128, NN / 128, 2), 256, 0, stream>>>(
                Hh, Hl, wTh, wTl, z, NN, Nout, 256);
            attn_scores<<<NN, 256, 0, stream>>>(z, ass[l], ads[l], s_src, s_dst, Nout, Nout / 4);
            if (l < 2)
                gat_aggregate<256, 64><<<NN / 4, 256, 0, stream>>>(z, row_ofs, col, s_src,
                                                                   s_dst, bs[l], Hs[l + 1]);
            else
                gat_aggregate<128, 32><<<NN / 4, 256, 0, stream>>>(z, row_ofs, col, s_src,
                                                                   s_dst, bs[l], Hs[l + 1]);
        }

        // ---- GIP normalize (hi/lo concat, fused md0 accumulation) + fused grams ----
        hipMemsetAsync(md0D, 0, 256, stream);
        hipMemsetAsync(md0T, 0, 256, stream);
        for (int l = 0; l < 4; l++) {
            gip_norm_split<<<DSZ, Fo[l], 0, stream>>>(Hs[l], YdH, YdL, rbD + l * DSZ,
                                                      md0D + l, 1.f / DSZ, Fo[l], l * 256);
            gip_norm_split<<<TSZ, Fo[l], 0, stream>>>(Hs[l] + (size_t)DSZ * Fo[l], YtH, YtL,
                                                      rbT + l * TSZ, md0T + l, 1.f / TSZ,
                                                      Fo[l], l * 256);
        }
        gram_fused<<<dim3(DSZ / 128, DSZ / 128), 256, 0, stream>>>(YdH, YdL, dsim, drug_k,
                                                                   rbD, md0D, DSZ);
        gram_fused<<<dim3(TSZ / 128, TSZ / 128), 256, 0, stream>>>(YtH, YtL, tsim, tgt_k,
                                                                   rbT, md0T, TSZ);

        // ---- normalized_kernel (fused hi/lo split) ----
        init_min<<<1, 64, 0, stream>>>(minb);
        min_nonzero<<<1024, 256, 0, stream>>>(drug_k, minb + 0, (size_t)DSZ * DSZ);
        diag_abs<<<(DSZ + 255) / 256, 256, 0, stream>>>(drug_k, dbD, DSZ);
        normdiv_split<<<dim3(DSZ / 256, DSZ), 256, 0, stream>>>(drug_k, dbD, minb + 0,
                                                                dkh, dkl, DSZ);
        min_nonzero<<<1024, 256, 0, stream>>>(tgt_k, minb + 1, (size_t)TSZ * TSZ);
        diag_abs<<<(TSZ + 255) / 256, 256, 0, stream>>>(tgt_k, dbT, TSZ);
        normdiv_split<<<dim3(TSZ / 256, TSZ), 256, 0, stream>>>(tgt_k, dbT, minb + 1,
                                                                tkh, tkl, TSZ);

        // ---- fused finals: out = 0.5*(dk@a1 + a2^T@tk) directly ----
        split_T<<<dim3(TSZ / 32, DSZ / 32), 256, 0, stream>>>(alpha1, a1Th, a1Tl, DSZ, TSZ);
        split_T<<<dim3(DSZ / 32, TSZ / 32), 256, 0, stream>>>(alpha2, a2Th, a2Tl, TSZ, DSZ);
        final_fused<<<dim3(TSZ / 128, DSZ / 128), 256, 0, stream>>>(
            dkh, dkl, a1Th, a1Tl, a2Th, a2Tl, tkh, tkl, out);
    } else {
        // ---- fallback: fp32 SIMT everywhere ----
        hipMemsetAsync(z, 0, (size_t)NN * 256 * 4, stream);
        gemm64<true><<<dim3(256 / 64, NN / 64, 8), 256, 0, stream>>>(x, W1, z, NN, 256, NN);
        attn_scores<<<NN, 256, 0, stream>>>(z, as1, ad1, s_src, s_dst, 256, 64);
        gat_aggregate<256, 64><<<NN / 4, 256, 0, stream>>>(z, row_ofs, col, s_src, s_dst, b1, H1);
        gemm64<false><<<dim3(256 / 64, NN / 64), 256, 0, stream>>>(H1, W2, z, NN, 256, 256);
        attn_scores<<<NN, 256, 0, stream>>>(z, as2, ad2, s_src, s_dst, 256, 64);
        gat_aggregate<256, 64><<<NN / 4, 256, 0, stream>>>(z, row_ofs, col, s_src, s_dst, b2, H2);
        gemm64<false><<<dim3(256 / 64, NN / 64), 256, 0, stream>>>(H2, W3, z, NN, 256, 256);
        attn_scores<<<NN, 256, 0, stream>>>(z, as3, ad3, s_src, s_dst, 256, 64);
        gat_aggregate<256, 64><<<NN / 4, 256, 0, stream>>>(z, row_ofs, col, s_src, s_dst, b3, H3);
        gemm64<false><<<dim3(128 / 64, NN / 64), 256, 0, stream>>>(H3, W4, z, NN, 128, 256);
        attn_scores<<<NN, 256, 0, stream>>>(z, as4, ad4, s_src, s_dst, 128, 32);
        gat_aggregate<128, 32><<<NN / 4, 256, 0, stream>>>(z, row_ofs, col, s_src, s_dst, b4, H4);

        scale_copy<<<4096, 256, 0, stream>>>(dsim, drug_k, 0.2f, (size_t)DSZ * DSZ);
        scale_copy<<<8192, 256, 0, stream>>>(tsim, tgt_k, 0.2f, (size_t)TSZ * TSZ);
        for (int l = 0; l < 4; l++) {
            gip_norm<<<DSZ, Fo[l], 0, stream>>>(Hs[l], Yn_fb, rbT, Fo[l]);
            mean_reduce<<<1, 1024, 0, stream>>>(rbT, md0T, DSZ);
            gram64<<<dim3(DSZ / 64, DSZ / 64), 256, 0, stream>>>(Yn_fb, drug_k, rbT, md0T,
                                                                 PSv[l], DSZ, Fo[l]);
            gip_norm<<<TSZ, Fo[l], 0, stream>>>(Hs[l] + (size_t)DSZ * Fo[l], Yn_fb, rbT, Fo[l]);
            mean_reduce<<<1, 1024, 0, stream>>>(rbT, md0T, TSZ);
            gram64<<<dim3(TSZ / 64, TSZ / 64), 256, 0, stream>>>(Yn_fb, tgt_k, rbT, md0T,
                                                                 PSv[l], TSZ, Fo[l]);
        }
        init_min<<<1, 64, 0, stream>>>(minb);
        min_nonzero<<<1024, 256, 0, stream>>>(drug_k, minb + 0, (size_t)DSZ * DSZ);
        diag_abs<<<(DSZ + 255) / 256, 256, 0, stream>>>(drug_k, dbD, DSZ);
        normdiv<<<dim3(DSZ / 256, DSZ), 256, 0, stream>>>(drug_k, dbD, minb + 0, DSZ);
        min_nonzero<<<1024, 256, 0, stream>>>(tgt_k, minb + 1, (size_t)TSZ * TSZ);
        diag_abs<<<(TSZ + 255) / 256, 256, 0, stream>>>(tgt_k, dbT, TSZ);
        normdiv<<<dim3(TSZ / 256, TSZ), 256, 0, stream>>>(tgt_k, dbT, minb + 1, TSZ);
        gemm64<false><<<dim3(TSZ / 64, DSZ / 64), 256, 0, stream>>>(drug_k, alpha1, out,
                                                                    DSZ, TSZ, DSZ);
        gemm64<false><<<dim3(DSZ / 64, TSZ / 64), 256, 0, stream>>>(tgt_k, alpha2, Bmat,
                                                                    TSZ, DSZ, TSZ);
        combine<<<dim3(TSZ / 32, DSZ / 32), 256, 0, stream>>>(out, Bmat);
    }
}